// Round 18
// baseline (176.177 us; speedup 1.0000x reference)
//
#include <hip/hip_runtime.h>

#define HIDDEN 64
#define BETA 0.01f
#define GAMMA 0.01f

#define BUCKET_SHIFT 6                 // 64 users per bucket
#define BUCKET_W     (1 << BUCKET_SHIFT)
#define TILE_E       8192              // entries per partition tile
#define CAP          3072              // LDS entry buffer (24 KB); mean 2560

__device__ inline unsigned short f2bf(float f) {   // RNE float->bf16
    unsigned x = __float_as_uint(f);
    return (unsigned short)((x + 0x7fffu + ((x >> 16) & 1u)) >> 16);
}
__device__ inline float bf2f(unsigned short b) {
    return __uint_as_float(((unsigned)b) << 16);
}
__device__ inline float bflo(unsigned w) { return __uint_as_float(w << 16); }
__device__ inline float bfhi(unsigned w) {
    return __uint_as_float(w & 0xffff0000u);
}

// ---------------------------------------------------------------------------
// Fused encode, register-blocked: each wave owns 4 movies; W columns loaded
// once and reused x4. Phase 1: h rows -> LDS. Phase 2: P/Q (bf16).
// ---------------------------------------------------------------------------
__global__ void __launch_bounds__(256)
encode_kernel(const float* __restrict__ features,
              const float* __restrict__ W_enc,
              const float* __restrict__ b_enc,
              const float* __restrict__ W_p,
              const float* __restrict__ W_q,
              unsigned short* __restrict__ Ph,
              unsigned short* __restrict__ Qh,
              float* __restrict__ partials, int slot_base,
              int num_movies, int in_feats) {
    __shared__ float hs[16][HIDDEN];           // 4 KB
    const int tid = threadIdx.x;
    const int j = tid & 63;
    const int wv = tid >> 6;                   // wave 0..3
    const int m0 = blockIdx.x * 16 + wv * 4;   // this wave's 4 movies

    const int c0 = min(m0 + 0, num_movies - 1);
    const int c1 = min(m0 + 1, num_movies - 1);
    const int c2 = min(m0 + 2, num_movies - 1);
    const int c3 = min(m0 + 3, num_movies - 1);
    const float* fr0 = features + (size_t)c0 * in_feats;
    const float* fr1 = features + (size_t)c1 * in_feats;
    const float* fr2 = features + (size_t)c2 * in_feats;
    const float* fr3 = features + (size_t)c3 * in_feats;

    float h0 = 0.0f, h1 = 0.0f, h2 = 0.0f, h3 = 0.0f;
    #pragma unroll 4
    for (int f = 0; f < in_feats; f += 4) {
        const float w_a = W_enc[(f + 0) * HIDDEN + j];
        const float w_b = W_enc[(f + 1) * HIDDEN + j];
        const float w_c = W_enc[(f + 2) * HIDDEN + j];
        const float w_d = W_enc[(f + 3) * HIDDEN + j];
        const float4 a0 = *(const float4*)(fr0 + f);
        const float4 a1 = *(const float4*)(fr1 + f);
        const float4 a2 = *(const float4*)(fr2 + f);
        const float4 a3 = *(const float4*)(fr3 + f);
        h0 = fmaf(a0.x, w_a, h0); h0 = fmaf(a0.y, w_b, h0);
        h0 = fmaf(a0.z, w_c, h0); h0 = fmaf(a0.w, w_d, h0);
        h1 = fmaf(a1.x, w_a, h1); h1 = fmaf(a1.y, w_b, h1);
        h1 = fmaf(a1.z, w_c, h1); h1 = fmaf(a1.w, w_d, h1);
        h2 = fmaf(a2.x, w_a, h2); h2 = fmaf(a2.y, w_b, h2);
        h2 = fmaf(a2.z, w_c, h2); h2 = fmaf(a2.w, w_d, h2);
        h3 = fmaf(a3.x, w_a, h3); h3 = fmaf(a3.y, w_b, h3);
        h3 = fmaf(a3.z, w_c, h3); h3 = fmaf(a3.w, w_d, h3);
    }
    const float be = b_enc[j];
    hs[wv * 4 + 0][j] = h0 + be;
    hs[wv * 4 + 1][j] = h1 + be;
    hs[wv * 4 + 2][j] = h2 + be;
    hs[wv * 4 + 3][j] = h3 + be;
    __syncthreads();

    float p0 = 0.0f, p1 = 0.0f, p2 = 0.0f, p3 = 0.0f;
    float q0 = 0.0f, q1 = 0.0f, q2 = 0.0f, q3 = 0.0f;
    #pragma unroll 4
    for (int f = 0; f < HIDDEN; f += 4) {
        const float wp0 = W_p[(f + 0) * HIDDEN + j];
        const float wp1 = W_p[(f + 1) * HIDDEN + j];
        const float wp2 = W_p[(f + 2) * HIDDEN + j];
        const float wp3 = W_p[(f + 3) * HIDDEN + j];
        const float wq0 = W_q[(f + 0) * HIDDEN + j];
        const float wq1 = W_q[(f + 1) * HIDDEN + j];
        const float wq2 = W_q[(f + 2) * HIDDEN + j];
        const float wq3 = W_q[(f + 3) * HIDDEN + j];
        const float4 v0 = *(const float4*)(&hs[wv * 4 + 0][f]);
        const float4 v1 = *(const float4*)(&hs[wv * 4 + 1][f]);
        const float4 v2 = *(const float4*)(&hs[wv * 4 + 2][f]);
        const float4 v3 = *(const float4*)(&hs[wv * 4 + 3][f]);
        p0 = fmaf(v0.x, wp0, p0); p0 = fmaf(v0.y, wp1, p0);
        p0 = fmaf(v0.z, wp2, p0); p0 = fmaf(v0.w, wp3, p0);
        q0 = fmaf(v0.x, wq0, q0); q0 = fmaf(v0.y, wq1, q0);
        q0 = fmaf(v0.z, wq2, q0); q0 = fmaf(v0.w, wq3, q0);
        p1 = fmaf(v1.x, wp0, p1); p1 = fmaf(v1.y, wp1, p1);
        p1 = fmaf(v1.z, wp2, p1); p1 = fmaf(v1.w, wp3, p1);
        q1 = fmaf(v1.x, wq0, q1); q1 = fmaf(v1.y, wq1, q1);
        q1 = fmaf(v1.z, wq2, q1); q1 = fmaf(v1.w, wq3, q1);
        p2 = fmaf(v2.x, wp0, p2); p2 = fmaf(v2.y, wp1, p2);
        p2 = fmaf(v2.z, wp2, p2); p2 = fmaf(v2.w, wp3, p2);
        q2 = fmaf(v2.x, wq0, q2); q2 = fmaf(v2.y, wq1, q2);
        q2 = fmaf(v2.z, wq2, q2); q2 = fmaf(v2.w, wq3, q2);
        p3 = fmaf(v3.x, wp0, p3); p3 = fmaf(v3.y, wp1, p3);
        p3 = fmaf(v3.z, wp2, p3); p3 = fmaf(v3.w, wp3, p3);
        q3 = fmaf(v3.x, wq0, q3); q3 = fmaf(v3.y, wq1, q3);
        q3 = fmaf(v3.z, wq2, q3); q3 = fmaf(v3.w, wq3, q3);
    }

    float reg = 0.0f;
    if (m0 + 0 < num_movies) {
        Ph[(size_t)(m0 + 0) * HIDDEN + j] = f2bf(p0);
        Qh[(size_t)(m0 + 0) * HIDDEN + j] = f2bf(q0);
        reg += p0 * p0 + q0 * q0;
    }
    if (m0 + 1 < num_movies) {
        Ph[(size_t)(m0 + 1) * HIDDEN + j] = f2bf(p1);
        Qh[(size_t)(m0 + 1) * HIDDEN + j] = f2bf(q1);
        reg += p1 * p1 + q1 * q1;
    }
    if (m0 + 2 < num_movies) {
        Ph[(size_t)(m0 + 2) * HIDDEN + j] = f2bf(p2);
        Qh[(size_t)(m0 + 2) * HIDDEN + j] = f2bf(q2);
        reg += p2 * p2 + q2 * q2;
    }
    if (m0 + 3 < num_movies) {
        Ph[(size_t)(m0 + 3) * HIDDEN + j] = f2bf(p3);
        Qh[(size_t)(m0 + 3) * HIDDEN + j] = f2bf(q3);
        reg += p3 * p3 + q3 * q3;
    }

    for (int off = 32; off; off >>= 1) reg += __shfl_down(reg, off);
    __shared__ float s_part[4];
    if (j == 0) s_part[wv] = reg;
    __syncthreads();
    if (tid == 0) {
        float t = (s_part[0] + s_part[1]) + (s_part[2] + s_part[3]);
        partials[slot_base + blockIdx.x] = 0.5f * BETA * t;
    }
}

// ---------------------------------------------------------------------------
// Per-tile LDS bucket histogram over nnz entries (nontemporal row reads).
// ---------------------------------------------------------------------------
__global__ void tilehist_kernel(const int* __restrict__ rows, int nnz,
                                int nbuckets, int ntiles,
                                unsigned* __restrict__ tileHist) {
    extern __shared__ unsigned hist[];
    const int t = blockIdx.x;
    const int tid = threadIdx.x;
    for (int i = tid; i < nbuckets; i += blockDim.x) hist[i] = 0;
    __syncthreads();

    const int base = t * TILE_E;
    const int kmax = TILE_E / 256;
    for (int k = 0; k < kmax; ++k) {
        const int e = base + k * 256 + tid;
        if (e < nnz) {
            const int r = __builtin_nontemporal_load(rows + e);
            atomicAdd(&hist[r >> BUCKET_SHIFT], 1u);
        }
    }
    __syncthreads();
    for (int i = tid; i < nbuckets; i += blockDim.x)
        tileHist[(size_t)i * ntiles + t] = hist[i];
}

// ---------------------------------------------------------------------------
// 2-level scan blocks. scantop widened to 1024 threads (n1 <= 1024).
// ---------------------------------------------------------------------------
__global__ void chunksum_kernel(const unsigned* __restrict__ src, int n,
                                unsigned* __restrict__ sums) {
    __shared__ unsigned s[256];
    const int t = threadIdx.x;
    const int i = blockIdx.x * 256 + t;
    s[t] = (i < n) ? src[i] : 0u;
    __syncthreads();
    for (int off = 128; off; off >>= 1) {
        if (t < off) s[t] += s[t + off];
        __syncthreads();
    }
    if (t == 0) sums[blockIdx.x] = s[0];
}

__global__ void __launch_bounds__(1024)
scantop_kernel(const unsigned* __restrict__ sums, int nchunks,
               unsigned* __restrict__ chunk_off,
               unsigned* __restrict__ offs, int n, int total) {
    __shared__ unsigned s[1024];
    const int t = threadIdx.x;
    unsigned x = (t < nchunks) ? sums[t] : 0u;
    s[t] = x;
    __syncthreads();
    for (int off = 1; off < 1024; off <<= 1) {
        unsigned v = (t >= off) ? s[t - off] : 0u;
        __syncthreads();
        s[t] += v;
        __syncthreads();
    }
    if (t < nchunks) chunk_off[t] = s[t] - x;   // exclusive
    if (t == 0) offs[n] = (unsigned)total;
}

__global__ void exscan_kernel(const unsigned* __restrict__ src, int n,
                              const unsigned* __restrict__ chunk_off,
                              unsigned* __restrict__ dst) {
    __shared__ unsigned s[256];
    const int t = threadIdx.x;
    const int i = blockIdx.x * 256 + t;
    unsigned x = (i < n) ? src[i] : 0u;
    s[t] = x;
    __syncthreads();
    for (int off = 1; off < 256; off <<= 1) {
        unsigned v = (t >= off) ? s[t - off] : 0u;
        __syncthreads();
        s[t] += v;
        __syncthreads();
    }
    if (i < n) dst[i] = chunk_off[blockIdx.x] + s[t] - x;
}

// ---------------------------------------------------------------------------
// Partition level 1: scatter nnz entries into bucket-major temp order.
// key = (user << 15) | col. Streaming inputs read nontemporally.
// ---------------------------------------------------------------------------
__global__ void partition_kernel(const int* __restrict__ rows,
                                 const int* __restrict__ cols,
                                 const float* __restrict__ vals, int nnz,
                                 int nbuckets, int ntiles,
                                 const unsigned* __restrict__ offsB,
                                 uint2* __restrict__ temp) {
    extern __shared__ unsigned smem[];          // hist[nb] then lofs[nb]
    unsigned* hist = smem;
    unsigned* lofs = smem + nbuckets;
    const int t = blockIdx.x;
    const int tid = threadIdx.x;
    for (int i = tid; i < nbuckets; i += blockDim.x) {
        hist[i] = 0;
        lofs[i] = offsB[(size_t)i * ntiles + t];
    }
    __syncthreads();

    const int base = t * TILE_E;
    const int kmax = TILE_E / 256;
    for (int k = 0; k < kmax; ++k) {
        const int e = base + k * 256 + tid;
        if (e < nnz) {
            const int r = __builtin_nontemporal_load(rows + e);
            const int c = __builtin_nontemporal_load(cols + e);
            const float v = __builtin_nontemporal_load(vals + e);
            const int b = r >> BUCKET_SHIFT;
            const unsigned lrank = atomicAdd(&hist[b], 1u);
            const unsigned dst = lofs[b] + lrank;
            const unsigned key = ((unsigned)r << 15) | (unsigned)c;
            temp[dst] = make_uint2(key, __float_as_uint(v));
        }
    }
}

// ---------------------------------------------------------------------------
// FUSED scatter+gather: WG per 64-user bucket (782 WGs, ~3/CU). Entries
// staged in 24 KB LDS; chunked (CAP) with RMW accumulation if oversized.
// ---------------------------------------------------------------------------
__global__ void __launch_bounds__(512)
scatter_gather_kernel(const uint2* __restrict__ temp,
                      const unsigned* __restrict__ offsB,
                      const unsigned short* __restrict__ Ph,
                      float* __restrict__ user_emb,
                      float* __restrict__ user_deg,
                      int ntiles, int num_users) {
    __shared__ uint2 ebuf[CAP];                 // 24 KB
    __shared__ int cnt[BUCKET_W];
    __shared__ int lstart[BUCKET_W];
    __shared__ int cur[BUCKET_W];

    const int b = blockIdx.x;
    const int tid = threadIdx.x;
    const int ubase = b << BUCKET_SHIFT;
    const int s0 = (int)offsB[(size_t)b * ntiles];
    const int s1 = (int)offsB[(size_t)(b + 1) * ntiles];

    const int wv = tid >> 6;            // wave 0..7
    const int lane = tid & 63;
    const int q = lane >> 4;            // quarter (entry slot)
    const int ql = lane & 15;           // comps 4ql..4ql+3

    bool first = true;
    int cbase = s0;
    do {
        const int cend = min(cbase + CAP, s1);

        // phase A: per-user count of this chunk
        if (tid < BUCKET_W) cnt[tid] = 0;
        __syncthreads();
        for (int s = cbase + tid; s < cend; s += 512)
            atomicAdd(&cnt[(int)(temp[s].x >> 15) - ubase], 1);
        __syncthreads();

        // exclusive scan of cnt[0..63]
        int x = 0;
        if (tid < BUCKET_W) { x = cnt[tid]; lstart[tid] = x; }
        __syncthreads();
        for (int off = 1; off < BUCKET_W; off <<= 1) {
            int v = 0;
            if (tid < BUCKET_W && tid >= off) v = lstart[tid - off];
            __syncthreads();
            if (tid < BUCKET_W) lstart[tid] += v;
            __syncthreads();
        }
        if (tid < BUCKET_W) {
            const int st = lstart[tid] - x;
            lstart[tid] = st;
            cur[tid] = st;
        }
        __syncthreads();

        // phase B: scatter chunk entries into LDS, user-contiguous
        for (int s = cbase + tid; s < cend; s += 512) {
            const uint2 e = temp[s];
            const int lu = (int)(e.x >> 15) - ubase;
            const int pos = atomicAdd(&cur[lu], 1);
            ebuf[pos] = make_uint2(e.x & 0x7fffu, e.y);
        }
        __syncthreads();

        // phase C: each wave gathers 8 users (quarter-wave layout)
        for (int k = 0; k < BUCKET_W / 8; ++k) {
            const int lu = wv * (BUCKET_W / 8) + k;
            const int gu = ubase + lu;
            if (gu >= num_users) break;
            const int ls = lstart[lu];
            const int le = cur[lu];
            float a0 = 0.0f, a1 = 0.0f, a2 = 0.0f, a3 = 0.0f, dA = 0.0f;
            float c0 = 0.0f, c1 = 0.0f, c2 = 0.0f, c3 = 0.0f, dB = 0.0f;
            int i = ls;
            for (; i + 7 < le; i += 8) {
                const uint2 eA = ebuf[i + q];
                const uint2 eB = ebuf[i + 4 + q];
                const uint2 wA =
                    *(const uint2*)(Ph + (size_t)eA.x * HIDDEN + 4 * ql);
                const uint2 wB =
                    *(const uint2*)(Ph + (size_t)eB.x * HIDDEN + 4 * ql);
                const float vA = __uint_as_float(eA.y);
                const float vB = __uint_as_float(eB.y);
                a0 = fmaf(vA, bflo(wA.x), a0);
                a1 = fmaf(vA, bfhi(wA.x), a1);
                a2 = fmaf(vA, bflo(wA.y), a2);
                a3 = fmaf(vA, bfhi(wA.y), a3);
                c0 = fmaf(vB, bflo(wB.x), c0);
                c1 = fmaf(vB, bfhi(wB.x), c1);
                c2 = fmaf(vB, bflo(wB.y), c2);
                c3 = fmaf(vB, bfhi(wB.y), c3);
                dA += vA;
                dB += vB;
            }
            for (; i + 3 < le; i += 4) {
                const uint2 eA = ebuf[i + q];
                const uint2 wA =
                    *(const uint2*)(Ph + (size_t)eA.x * HIDDEN + 4 * ql);
                const float vA = __uint_as_float(eA.y);
                a0 = fmaf(vA, bflo(wA.x), a0);
                a1 = fmaf(vA, bfhi(wA.x), a1);
                a2 = fmaf(vA, bflo(wA.y), a2);
                a3 = fmaf(vA, bfhi(wA.y), a3);
                dA += vA;
            }
            if (i + q < le) {
                const uint2 eA = ebuf[i + q];
                const uint2 wA =
                    *(const uint2*)(Ph + (size_t)eA.x * HIDDEN + 4 * ql);
                const float vA = __uint_as_float(eA.y);
                a0 = fmaf(vA, bflo(wA.x), a0);
                a1 = fmaf(vA, bfhi(wA.x), a1);
                a2 = fmaf(vA, bflo(wA.y), a2);
                a3 = fmaf(vA, bfhi(wA.y), a3);
                dA += vA;
            }

            float x0 = a0 + c0, x1 = a1 + c1, x2 = a2 + c2, x3 = a3 + c3;
            float deg = dA + dB;
            x0 += __shfl_xor(x0, 16); x0 += __shfl_xor(x0, 32);
            x1 += __shfl_xor(x1, 16); x1 += __shfl_xor(x1, 32);
            x2 += __shfl_xor(x2, 16); x2 += __shfl_xor(x2, 32);
            x3 += __shfl_xor(x3, 16); x3 += __shfl_xor(x3, 32);
            deg += __shfl_xor(deg, 16); deg += __shfl_xor(deg, 32);
            if (q == 0) {
                float4* dst = (float4*)(user_emb + (size_t)gu * HIDDEN + 4 * ql);
                if (first) {
                    *dst = make_float4(x0, x1, x2, x3);
                } else {
                    const float4 o = *dst;
                    *dst = make_float4(o.x + x0, o.y + x1, o.z + x2, o.w + x3);
                }
                if (ql == 0) {
                    if (first) user_deg[gu] = deg;
                    else user_deg[gu] += deg;
                }
            }
        }
        __syncthreads();    // ebuf reused next chunk
        first = false;
        cbase += CAP;
    } while (cbase < s1);
}

// ---------------------------------------------------------------------------
// 16 bf16 x 16 fp32 dot for one lane: q points at 32B (2 x uint4).
// ---------------------------------------------------------------------------
__device__ inline float dot16(const uint4* __restrict__ q,
                              const float* __restrict__ ue) {
    float d = 0.0f;
    #pragma unroll
    for (int h = 0; h < 2; ++h) {
        const uint4 v = q[h];
        const unsigned w0 = v.x, w1 = v.y, w2 = v.z, w3 = v.w;
        d = fmaf(ue[h * 8 + 0], bflo(w0), d);
        d = fmaf(ue[h * 8 + 1], bfhi(w0), d);
        d = fmaf(ue[h * 8 + 2], bflo(w1), d);
        d = fmaf(ue[h * 8 + 3], bfhi(w1), d);
        d = fmaf(ue[h * 8 + 4], bflo(w2), d);
        d = fmaf(ue[h * 8 + 5], bfhi(w2), d);
        d = fmaf(ue[h * 8 + 6], bflo(w3), d);
        d = fmaf(ue[h * 8 + 7], bfhi(w3), d);
    }
    return d;
}

// ---------------------------------------------------------------------------
// Pair loss, 4-lane group per pair (lane = 16 components), partial store.
// ---------------------------------------------------------------------------
template <int S>
__global__ void loss4_kernel(const float* __restrict__ user_emb,
                             const float* __restrict__ user_deg,
                             const unsigned short* __restrict__ Qh,
                             const float* __restrict__ b_u,
                             const float* __restrict__ b_i,
                             const int* __restrict__ rows,
                             const int* __restrict__ cols,
                             const int* __restrict__ pos_idx,
                             const int* __restrict__ neg_item_idx,
                             int num_pos,
                             float* __restrict__ partials, int slot_base) {
    const int tid = blockIdx.x * blockDim.x + threadIdx.x;
    const int g = tid >> 2;            // pair index
    const int l = tid & 3;             // lane-in-group: components [16l,16l+16)
    float acc = 0.0f;

    if (g < num_pos) {
        const int e = pos_idx[g];
        const int u = rows[e];
        const int ii = cols[e];
        const float invdeg = 1.0f / user_deg[u];

        float ue[16];
        {
            const float4* uep =
                (const float4*)(user_emb + (size_t)u * HIDDEN + l * 16);
            #pragma unroll
            for (int k = 0; k < 4; ++k) {
                const float4 t4 = uep[k];
                ue[4 * k + 0] = t4.x * invdeg;
                ue[4 * k + 1] = t4.y * invdeg;
                ue[4 * k + 2] = t4.z * invdeg;
                ue[4 * k + 3] = t4.w * invdeg;
            }
        }

        int jarr[S];
        float part[1 + S];
        part[0] = dot16((const uint4*)(Qh + (size_t)ii * HIDDEN + l * 16), ue);
        #pragma unroll
        for (int s = 0; s < S; ++s) {
            const int j = neg_item_idx[(size_t)g * S + s];
            jarr[s] = j;
            part[1 + s] =
                dot16((const uint4*)(Qh + (size_t)j * HIDDEN + l * 16), ue);
        }

        #pragma unroll
        for (int k = 0; k < 1 + S; ++k) {
            part[k] += __shfl_xor(part[k], 1);
            part[k] += __shfl_xor(part[k], 2);
        }

        if (l == 0) {
            const float bu = b_u[u];
            const float r = bu + b_i[ii] + part[0];
            #pragma unroll
            for (int s = 0; s < S; ++s) {
                const float nr = bu + b_i[jarr[s]] + part[1 + s];
                const float diff = 1.0f - (r - nr);
                acc += 0.5f * diff * diff;
            }
        }
    }

    for (int off = 32; off; off >>= 1) acc += __shfl_down(acc, off);
    __shared__ float s_part[16];
    const int wave = threadIdx.x >> 6;
    const int lane = threadIdx.x & 63;
    if (lane == 0) s_part[wave] = acc;
    __syncthreads();
    if (threadIdx.x == 0) {
        float t = 0.0f;
        const int nw = blockDim.x >> 6;
        for (int w = 0; w < nw; ++w) t += s_part[w];
        partials[slot_base + blockIdx.x] = t;
    }
}

// generic fallback (thread per pair), only used if S != 5
__global__ void loss_generic_kernel(const float* __restrict__ user_emb,
                                    const float* __restrict__ user_deg,
                                    const unsigned short* __restrict__ Qh,
                                    const float* __restrict__ b_u,
                                    const float* __restrict__ b_i,
                                    const int* __restrict__ rows,
                                    const int* __restrict__ cols,
                                    const int* __restrict__ pos_idx,
                                    const int* __restrict__ neg_item_idx,
                                    int num_pos, int S,
                                    float* __restrict__ partials,
                                    int slot_base) {
    const int p = blockIdx.x * blockDim.x + threadIdx.x;
    float acc = 0.0f;
    if (p < num_pos) {
        const int e = pos_idx[p];
        const int u = rows[e];
        const int ii = cols[e];
        const float invdeg = 1.0f / user_deg[u];
        float ue[HIDDEN];
        #pragma unroll
        for (int kk = 0; kk < HIDDEN; ++kk)
            ue[kk] = user_emb[(size_t)u * HIDDEN + kk] * invdeg;
        const float bu = b_u[u];
        float dot = 0.0f;
        #pragma unroll
        for (int kk = 0; kk < HIDDEN; ++kk)
            dot = fmaf(ue[kk], bf2f(Qh[(size_t)ii * HIDDEN + kk]), dot);
        const float rr = bu + b_i[ii] + dot;
        for (int s = 0; s < S; ++s) {
            const int j = neg_item_idx[(size_t)p * S + s];
            float dn = 0.0f;
            #pragma unroll
            for (int kk = 0; kk < HIDDEN; ++kk)
                dn = fmaf(ue[kk], bf2f(Qh[(size_t)j * HIDDEN + kk]), dn);
            const float nr = bu + b_i[j] + dn;
            const float diff = 1.0f - (rr - nr);
            acc += 0.5f * diff * diff;
        }
    }
    for (int off = 32; off; off >>= 1) acc += __shfl_down(acc, off);
    __shared__ float s_part[16];
    const int wave = threadIdx.x >> 6;
    const int lane = threadIdx.x & 63;
    if (lane == 0) s_part[wave] = acc;
    __syncthreads();
    if (threadIdx.x == 0) {
        float t = 0.0f;
        const int nw = blockDim.x >> 6;
        for (int w = 0; w < nw; ++w) t += s_part[w];
        partials[slot_base + blockIdx.x] = t;
    }
}

// ---------------------------------------------------------------------------
// Final reduction: sum partial slots + GAMMA bias regularizer -> out[0].
// ---------------------------------------------------------------------------
__global__ void __launch_bounds__(1024)
final_reduce_kernel(const float* __restrict__ partials, int n,
                    const float* __restrict__ b_u, int nu,
                    const float* __restrict__ b_i, int ni,
                    float* __restrict__ out) {
    __shared__ float s[1024];
    const int t = threadIdx.x;
    float a = 0.0f;
    for (int i = t; i < n; i += 1024) a += partials[i];
    float r = 0.0f;
    for (int i = t; i < nu; i += 1024) {
        const float v = b_u[i];
        r = fmaf(v, v, r);
    }
    for (int i = t; i < ni; i += 1024) {
        const float v = b_i[i];
        r = fmaf(v, v, r);
    }
    s[t] = a + 0.5f * GAMMA * r;
    __syncthreads();
    for (int off = 512; off; off >>= 1) {
        if (t < off) s[t] += s[t + off];
        __syncthreads();
    }
    if (t == 0) out[0] = s[0];
}

// ---------------------------------------------------------------------------
extern "C" void kernel_launch(void* const* d_in, const int* in_sizes, int n_in,
                              void* d_out, int out_size, void* d_ws, size_t ws_size,
                              hipStream_t stream) {
    const float* features     = (const float*)d_in[0];
    const float* W_enc        = (const float*)d_in[1];
    const float* b_enc        = (const float*)d_in[2];
    const float* W_p          = (const float*)d_in[3];
    const float* W_q          = (const float*)d_in[4];
    const float* b_u          = (const float*)d_in[5];
    const float* b_i          = (const float*)d_in[6];
    const float* vals         = (const float*)d_in[7];
    const int*   rows         = (const int*)d_in[8];
    const int*   cols         = (const int*)d_in[9];
    const int*   pos_idx      = (const int*)d_in[10];
    const int*   neg_item_idx = (const int*)d_in[11];

    const int num_users  = in_sizes[5];                 // 50000
    const int num_movies = in_sizes[6];                 // 20000
    const int in_feats   = in_sizes[0] / num_movies;    // 128
    const int nnz        = in_sizes[7];                 // 2000000
    const int num_pos    = in_sizes[10];                // 200000
    const int S          = in_sizes[11] / num_pos;      // 5

    const int nbB    = (num_users + BUCKET_W - 1) >> BUCKET_SHIFT;  // 782
    const int ntiles = (nnz + TILE_E - 1) / TILE_E;                 // 245
    const int scanNB = nbB * ntiles;                                // 191590
    const int n1b    = (scanNB + 255) / 256;                        // 749 <= 1024

    const int enc_blocks  = (num_movies + 15) / 16;                 // 1250
    const int loss_blocks = (S == 5) ? (int)(((size_t)num_pos * 4 + 255) / 256)
                                     : (num_pos + 255) / 256;
    const int slot_pq   = 0;
    const int slot_loss = enc_blocks;
    const int n_slots   = enc_blocks + loss_blocks;

    // workspace layout (256B-aligned)
    auto align256 = [](size_t x) { return (x + 255) & ~(size_t)255; };
    char* ws = (char*)d_ws;
    size_t off = 0;
    unsigned short* Ph = (unsigned short*)(ws + off);
    off += align256((size_t)num_movies * HIDDEN * 2);
    unsigned short* Qh = (unsigned short*)(ws + off);
    off += align256((size_t)num_movies * HIDDEN * 2);
    uint2* temp     = (uint2*)(ws + off); off += align256((size_t)nnz * 8);
    float* user_emb = (float*)(ws + off); off += align256((size_t)num_users * HIDDEN * 4);
    float* user_deg = (float*)(ws + off); off += align256((size_t)num_users * 4);
    unsigned* tileHistB = (unsigned*)(ws + off); off += align256((size_t)scanNB * 4);
    unsigned* offsB     = (unsigned*)(ws + off); off += align256((size_t)(scanNB + 1) * 4);
    unsigned* sums_b    = (unsigned*)(ws + off); off += align256(1024 * 4);
    unsigned* top_b     = (unsigned*)(ws + off); off += align256(1024 * 4);
    float* partials     = (float*)(ws + off);    off += align256((size_t)n_slots * 4);

    float* out = (float*)d_out;

    // fused register-blocked encode -> Ph/Qh (bf16) + regularizer partials
    encode_kernel<<<enc_blocks, 256, 0, stream>>>(
        features, W_enc, b_enc, W_p, W_q, Ph, Qh, partials, slot_pq,
        num_movies, in_feats);

    // nnz bucket histogram + scan -> offsB
    tilehist_kernel<<<ntiles, 256, (size_t)nbB * 4, stream>>>(
        rows, nnz, nbB, ntiles, tileHistB);
    chunksum_kernel<<<n1b, 256, 0, stream>>>(tileHistB, scanNB, sums_b);
    scantop_kernel<<<1, 1024, 0, stream>>>(sums_b, n1b, top_b, offsB, scanNB, nnz);
    exscan_kernel<<<n1b, 256, 0, stream>>>(tileHistB, scanNB, top_b, offsB);

    // partition -> bucket-major temp
    partition_kernel<<<ntiles, 256, (size_t)nbB * 8, stream>>>(
        rows, cols, vals, nnz, nbB, ntiles, offsB, temp);

    // fused LDS scatter + register gather
    scatter_gather_kernel<<<nbB, 512, 0, stream>>>(
        temp, offsB, Ph, user_emb, user_deg, ntiles, num_users);

    // pair loss -> per-block partials
    if (S == 5) {
        loss4_kernel<5><<<loss_blocks, 256, 0, stream>>>(
            user_emb, user_deg, Qh, b_u, b_i, rows, cols, pos_idx,
            neg_item_idx, num_pos, partials, slot_loss);
    } else {
        loss_generic_kernel<<<loss_blocks, 256, 0, stream>>>(
            user_emb, user_deg, Qh, b_u, b_i, rows, cols, pos_idx,
            neg_item_idx, num_pos, S, partials, slot_loss);
    }

    // final: partial slots + GAMMA bias regularizer
    final_reduce_kernel<<<1, 1024, 0, stream>>>(partials, n_slots,
                                                b_u, num_users,
                                                b_i, num_movies, out);
}

// Round 19
// 166.894 us; speedup vs baseline: 1.0556x; 1.0556x over previous
//
#include <hip/hip_runtime.h>

#define HIDDEN 64
#define BETA 0.01f
#define GAMMA 0.01f

#define BUCKET_SHIFT 7                 // 128 users per bucket
#define BUCKET_W     (1 << BUCKET_SHIFT)
#define TILE_E       8192              // entries per partition tile
#define CAP          6144              // LDS entry buffer (48 KB); mean 5120
#define EPT          (CAP / 512)       // 12 entries per thread per chunk

__device__ inline unsigned short f2bf(float f) {   // RNE float->bf16
    unsigned x = __float_as_uint(f);
    return (unsigned short)((x + 0x7fffu + ((x >> 16) & 1u)) >> 16);
}
__device__ inline float bf2f(unsigned short b) {
    return __uint_as_float(((unsigned)b) << 16);
}
__device__ inline float bflo(unsigned w) { return __uint_as_float(w << 16); }
__device__ inline float bfhi(unsigned w) {
    return __uint_as_float(w & 0xffff0000u);
}

// ---------------------------------------------------------------------------
// Fused encode, register-blocked: each wave owns 4 movies; W columns loaded
// once and reused x4. Phase 1: h rows -> LDS. Phase 2: P/Q (bf16).
// ---------------------------------------------------------------------------
__global__ void __launch_bounds__(256)
encode_kernel(const float* __restrict__ features,
              const float* __restrict__ W_enc,
              const float* __restrict__ b_enc,
              const float* __restrict__ W_p,
              const float* __restrict__ W_q,
              unsigned short* __restrict__ Ph,
              unsigned short* __restrict__ Qh,
              float* __restrict__ partials, int slot_base,
              int num_movies, int in_feats) {
    __shared__ float hs[16][HIDDEN];           // 4 KB
    const int tid = threadIdx.x;
    const int j = tid & 63;
    const int wv = tid >> 6;                   // wave 0..3
    const int m0 = blockIdx.x * 16 + wv * 4;   // this wave's 4 movies

    const int c0 = min(m0 + 0, num_movies - 1);
    const int c1 = min(m0 + 1, num_movies - 1);
    const int c2 = min(m0 + 2, num_movies - 1);
    const int c3 = min(m0 + 3, num_movies - 1);
    const float* fr0 = features + (size_t)c0 * in_feats;
    const float* fr1 = features + (size_t)c1 * in_feats;
    const float* fr2 = features + (size_t)c2 * in_feats;
    const float* fr3 = features + (size_t)c3 * in_feats;

    float h0 = 0.0f, h1 = 0.0f, h2 = 0.0f, h3 = 0.0f;
    #pragma unroll 4
    for (int f = 0; f < in_feats; f += 4) {
        const float w_a = W_enc[(f + 0) * HIDDEN + j];
        const float w_b = W_enc[(f + 1) * HIDDEN + j];
        const float w_c = W_enc[(f + 2) * HIDDEN + j];
        const float w_d = W_enc[(f + 3) * HIDDEN + j];
        const float4 a0 = *(const float4*)(fr0 + f);
        const float4 a1 = *(const float4*)(fr1 + f);
        const float4 a2 = *(const float4*)(fr2 + f);
        const float4 a3 = *(const float4*)(fr3 + f);
        h0 = fmaf(a0.x, w_a, h0); h0 = fmaf(a0.y, w_b, h0);
        h0 = fmaf(a0.z, w_c, h0); h0 = fmaf(a0.w, w_d, h0);
        h1 = fmaf(a1.x, w_a, h1); h1 = fmaf(a1.y, w_b, h1);
        h1 = fmaf(a1.z, w_c, h1); h1 = fmaf(a1.w, w_d, h1);
        h2 = fmaf(a2.x, w_a, h2); h2 = fmaf(a2.y, w_b, h2);
        h2 = fmaf(a2.z, w_c, h2); h2 = fmaf(a2.w, w_d, h2);
        h3 = fmaf(a3.x, w_a, h3); h3 = fmaf(a3.y, w_b, h3);
        h3 = fmaf(a3.z, w_c, h3); h3 = fmaf(a3.w, w_d, h3);
    }
    const float be = b_enc[j];
    hs[wv * 4 + 0][j] = h0 + be;
    hs[wv * 4 + 1][j] = h1 + be;
    hs[wv * 4 + 2][j] = h2 + be;
    hs[wv * 4 + 3][j] = h3 + be;
    __syncthreads();

    float p0 = 0.0f, p1 = 0.0f, p2 = 0.0f, p3 = 0.0f;
    float q0 = 0.0f, q1 = 0.0f, q2 = 0.0f, q3 = 0.0f;
    #pragma unroll 4
    for (int f = 0; f < HIDDEN; f += 4) {
        const float wp0 = W_p[(f + 0) * HIDDEN + j];
        const float wp1 = W_p[(f + 1) * HIDDEN + j];
        const float wp2 = W_p[(f + 2) * HIDDEN + j];
        const float wp3 = W_p[(f + 3) * HIDDEN + j];
        const float wq0 = W_q[(f + 0) * HIDDEN + j];
        const float wq1 = W_q[(f + 1) * HIDDEN + j];
        const float wq2 = W_q[(f + 2) * HIDDEN + j];
        const float wq3 = W_q[(f + 3) * HIDDEN + j];
        const float4 v0 = *(const float4*)(&hs[wv * 4 + 0][f]);
        const float4 v1 = *(const float4*)(&hs[wv * 4 + 1][f]);
        const float4 v2 = *(const float4*)(&hs[wv * 4 + 2][f]);
        const float4 v3 = *(const float4*)(&hs[wv * 4 + 3][f]);
        p0 = fmaf(v0.x, wp0, p0); p0 = fmaf(v0.y, wp1, p0);
        p0 = fmaf(v0.z, wp2, p0); p0 = fmaf(v0.w, wp3, p0);
        q0 = fmaf(v0.x, wq0, q0); q0 = fmaf(v0.y, wq1, q0);
        q0 = fmaf(v0.z, wq2, q0); q0 = fmaf(v0.w, wq3, q0);
        p1 = fmaf(v1.x, wp0, p1); p1 = fmaf(v1.y, wp1, p1);
        p1 = fmaf(v1.z, wp2, p1); p1 = fmaf(v1.w, wp3, p1);
        q1 = fmaf(v1.x, wq0, q1); q1 = fmaf(v1.y, wq1, q1);
        q1 = fmaf(v1.z, wq2, q1); q1 = fmaf(v1.w, wq3, q1);
        p2 = fmaf(v2.x, wp0, p2); p2 = fmaf(v2.y, wp1, p2);
        p2 = fmaf(v2.z, wp2, p2); p2 = fmaf(v2.w, wp3, p2);
        q2 = fmaf(v2.x, wq0, q2); q2 = fmaf(v2.y, wq1, q2);
        q2 = fmaf(v2.z, wq2, q2); q2 = fmaf(v2.w, wq3, q2);
        p3 = fmaf(v3.x, wp0, p3); p3 = fmaf(v3.y, wp1, p3);
        p3 = fmaf(v3.z, wp2, p3); p3 = fmaf(v3.w, wp3, p3);
        q3 = fmaf(v3.x, wq0, q3); q3 = fmaf(v3.y, wq1, q3);
        q3 = fmaf(v3.z, wq2, q3); q3 = fmaf(v3.w, wq3, q3);
    }

    float reg = 0.0f;
    if (m0 + 0 < num_movies) {
        Ph[(size_t)(m0 + 0) * HIDDEN + j] = f2bf(p0);
        Qh[(size_t)(m0 + 0) * HIDDEN + j] = f2bf(q0);
        reg += p0 * p0 + q0 * q0;
    }
    if (m0 + 1 < num_movies) {
        Ph[(size_t)(m0 + 1) * HIDDEN + j] = f2bf(p1);
        Qh[(size_t)(m0 + 1) * HIDDEN + j] = f2bf(q1);
        reg += p1 * p1 + q1 * q1;
    }
    if (m0 + 2 < num_movies) {
        Ph[(size_t)(m0 + 2) * HIDDEN + j] = f2bf(p2);
        Qh[(size_t)(m0 + 2) * HIDDEN + j] = f2bf(q2);
        reg += p2 * p2 + q2 * q2;
    }
    if (m0 + 3 < num_movies) {
        Ph[(size_t)(m0 + 3) * HIDDEN + j] = f2bf(p3);
        Qh[(size_t)(m0 + 3) * HIDDEN + j] = f2bf(q3);
        reg += p3 * p3 + q3 * q3;
    }

    for (int off = 32; off; off >>= 1) reg += __shfl_down(reg, off);
    __shared__ float s_part[4];
    if (j == 0) s_part[wv] = reg;
    __syncthreads();
    if (tid == 0) {
        float t = (s_part[0] + s_part[1]) + (s_part[2] + s_part[3]);
        partials[slot_base + blockIdx.x] = 0.5f * BETA * t;
    }
}

// ---------------------------------------------------------------------------
// Per-tile LDS bucket histogram over nnz entries (nontemporal row reads).
// ---------------------------------------------------------------------------
__global__ void tilehist_kernel(const int* __restrict__ rows, int nnz,
                                int nbuckets, int ntiles,
                                unsigned* __restrict__ tileHist) {
    extern __shared__ unsigned hist[];
    const int t = blockIdx.x;
    const int tid = threadIdx.x;
    for (int i = tid; i < nbuckets; i += blockDim.x) hist[i] = 0;
    __syncthreads();

    const int base = t * TILE_E;
    const int kmax = TILE_E / 256;
    for (int k = 0; k < kmax; ++k) {
        const int e = base + k * 256 + tid;
        if (e < nnz) {
            const int r = __builtin_nontemporal_load(rows + e);
            atomicAdd(&hist[r >> BUCKET_SHIFT], 1u);
        }
    }
    __syncthreads();
    for (int i = tid; i < nbuckets; i += blockDim.x)
        tileHist[(size_t)i * ntiles + t] = hist[i];
}

// ---------------------------------------------------------------------------
// 2-level scan blocks.
// ---------------------------------------------------------------------------
__global__ void chunksum_kernel(const unsigned* __restrict__ src, int n,
                                unsigned* __restrict__ sums) {
    __shared__ unsigned s[256];
    const int t = threadIdx.x;
    const int i = blockIdx.x * 256 + t;
    s[t] = (i < n) ? src[i] : 0u;
    __syncthreads();
    for (int off = 128; off; off >>= 1) {
        if (t < off) s[t] += s[t + off];
        __syncthreads();
    }
    if (t == 0) sums[blockIdx.x] = s[0];
}

__global__ void __launch_bounds__(512)
scantop_kernel(const unsigned* __restrict__ sums, int nchunks,
               unsigned* __restrict__ chunk_off,
               unsigned* __restrict__ offs, int n, int total) {
    __shared__ unsigned s[512];
    const int t = threadIdx.x;
    unsigned x = (t < nchunks) ? sums[t] : 0u;
    s[t] = x;
    __syncthreads();
    for (int off = 1; off < 512; off <<= 1) {
        unsigned v = (t >= off) ? s[t - off] : 0u;
        __syncthreads();
        s[t] += v;
        __syncthreads();
    }
    if (t < nchunks) chunk_off[t] = s[t] - x;   // exclusive
    if (t == 0) offs[n] = (unsigned)total;
}

__global__ void exscan_kernel(const unsigned* __restrict__ src, int n,
                              const unsigned* __restrict__ chunk_off,
                              unsigned* __restrict__ dst) {
    __shared__ unsigned s[256];
    const int t = threadIdx.x;
    const int i = blockIdx.x * 256 + t;
    unsigned x = (i < n) ? src[i] : 0u;
    s[t] = x;
    __syncthreads();
    for (int off = 1; off < 256; off <<= 1) {
        unsigned v = (t >= off) ? s[t - off] : 0u;
        __syncthreads();
        s[t] += v;
        __syncthreads();
    }
    if (i < n) dst[i] = chunk_off[blockIdx.x] + s[t] - x;
}

// ---------------------------------------------------------------------------
// Partition level 1: scatter nnz entries into bucket-major temp order.
// key = (user << 15) | col. Streaming inputs read nontemporally.
// ---------------------------------------------------------------------------
__global__ void partition_kernel(const int* __restrict__ rows,
                                 const int* __restrict__ cols,
                                 const float* __restrict__ vals, int nnz,
                                 int nbuckets, int ntiles,
                                 const unsigned* __restrict__ offsB,
                                 uint2* __restrict__ temp) {
    extern __shared__ unsigned smem[];          // hist[nb] then lofs[nb]
    unsigned* hist = smem;
    unsigned* lofs = smem + nbuckets;
    const int t = blockIdx.x;
    const int tid = threadIdx.x;
    for (int i = tid; i < nbuckets; i += blockDim.x) {
        hist[i] = 0;
        lofs[i] = offsB[(size_t)i * ntiles + t];
    }
    __syncthreads();

    const int base = t * TILE_E;
    const int kmax = TILE_E / 256;
    for (int k = 0; k < kmax; ++k) {
        const int e = base + k * 256 + tid;
        if (e < nnz) {
            const int r = __builtin_nontemporal_load(rows + e);
            const int c = __builtin_nontemporal_load(cols + e);
            const float v = __builtin_nontemporal_load(vals + e);
            const int b = r >> BUCKET_SHIFT;
            const unsigned lrank = atomicAdd(&hist[b], 1u);
            const unsigned dst = lofs[b] + lrank;
            const unsigned key = ((unsigned)r << 15) | (unsigned)c;
            temp[dst] = make_uint2(key, __float_as_uint(v));
        }
    }
}

// ---------------------------------------------------------------------------
// FUSED scatter+gather, register-staged: each thread reads its <=12 chunk
// entries from temp ONCE into registers; the counting pass's returning LDS
// atomic doubles as per-user rank, so the LDS scatter is a plain write.
// ---------------------------------------------------------------------------
__global__ void __launch_bounds__(512)
scatter_gather_kernel(const uint2* __restrict__ temp,
                      const unsigned* __restrict__ offsB,
                      const unsigned short* __restrict__ Ph,
                      float* __restrict__ user_emb,
                      float* __restrict__ user_deg,
                      int ntiles, int num_users) {
    __shared__ uint2 ebuf[CAP];                 // 48 KB
    __shared__ int cnt[BUCKET_W];
    __shared__ int lstart[BUCKET_W];

    const int b = blockIdx.x;
    const int tid = threadIdx.x;
    const int ubase = b << BUCKET_SHIFT;
    const int s0 = (int)offsB[(size_t)b * ntiles];
    const int s1 = (int)offsB[(size_t)(b + 1) * ntiles];

    const int wv = tid >> 6;            // wave 0..7
    const int lane = tid & 63;
    const int q = lane >> 4;            // quarter (entry slot)
    const int ql = lane & 15;           // comps 4ql..4ql+3

    bool first = true;
    int cbase = s0;
    do {
        const int cend = min(cbase + CAP, s1);

        // phase A: read entries into registers; returning atomic = rank
        uint2 ent[EPT];
        int rk[EPT];
        if (tid < BUCKET_W) cnt[tid] = 0;
        __syncthreads();
        #pragma unroll
        for (int k = 0; k < EPT; ++k) {
            const int s = cbase + tid + k * 512;
            if (s < cend) {
                const uint2 e = temp[s];
                ent[k] = e;
                rk[k] = atomicAdd(&cnt[(int)(e.x >> 15) - ubase], 1);
            }
        }
        __syncthreads();

        // exclusive scan of cnt -> lstart (cnt preserved for phase C)
        int x = 0;
        if (tid < BUCKET_W) { x = cnt[tid]; lstart[tid] = x; }
        __syncthreads();
        for (int off = 1; off < BUCKET_W; off <<= 1) {
            int v = 0;
            if (tid < BUCKET_W && tid >= off) v = lstart[tid - off];
            __syncthreads();
            if (tid < BUCKET_W) lstart[tid] += v;
            __syncthreads();
        }
        if (tid < BUCKET_W) lstart[tid] -= x;   // exclusive
        __syncthreads();

        // phase B: plain LDS writes at lstart[lu] + rank
        #pragma unroll
        for (int k = 0; k < EPT; ++k) {
            const int s = cbase + tid + k * 512;
            if (s < cend) {
                const int lu = (int)(ent[k].x >> 15) - ubase;
                ebuf[lstart[lu] + rk[k]] =
                    make_uint2(ent[k].x & 0x7fffu, ent[k].y);
            }
        }
        __syncthreads();

        // phase C: each wave gathers 16 users (quarter-wave layout)
        for (int k = 0; k < BUCKET_W / 8; ++k) {
            const int lu = wv * (BUCKET_W / 8) + k;
            const int gu = ubase + lu;
            if (gu >= num_users) break;
            const int ls = lstart[lu];
            const int le = ls + cnt[lu];
            float a0 = 0.0f, a1 = 0.0f, a2 = 0.0f, a3 = 0.0f, dA = 0.0f;
            float c0 = 0.0f, c1 = 0.0f, c2 = 0.0f, c3 = 0.0f, dB = 0.0f;
            int i = ls;
            for (; i + 7 < le; i += 8) {
                const uint2 eA = ebuf[i + q];
                const uint2 eB = ebuf[i + 4 + q];
                const uint2 wA =
                    *(const uint2*)(Ph + (size_t)eA.x * HIDDEN + 4 * ql);
                const uint2 wB =
                    *(const uint2*)(Ph + (size_t)eB.x * HIDDEN + 4 * ql);
                const float vA = __uint_as_float(eA.y);
                const float vB = __uint_as_float(eB.y);
                a0 = fmaf(vA, bflo(wA.x), a0);
                a1 = fmaf(vA, bfhi(wA.x), a1);
                a2 = fmaf(vA, bflo(wA.y), a2);
                a3 = fmaf(vA, bfhi(wA.y), a3);
                c0 = fmaf(vB, bflo(wB.x), c0);
                c1 = fmaf(vB, bfhi(wB.x), c1);
                c2 = fmaf(vB, bflo(wB.y), c2);
                c3 = fmaf(vB, bfhi(wB.y), c3);
                dA += vA;
                dB += vB;
            }
            for (; i + 3 < le; i += 4) {
                const uint2 eA = ebuf[i + q];
                const uint2 wA =
                    *(const uint2*)(Ph + (size_t)eA.x * HIDDEN + 4 * ql);
                const float vA = __uint_as_float(eA.y);
                a0 = fmaf(vA, bflo(wA.x), a0);
                a1 = fmaf(vA, bfhi(wA.x), a1);
                a2 = fmaf(vA, bflo(wA.y), a2);
                a3 = fmaf(vA, bfhi(wA.y), a3);
                dA += vA;
            }
            if (i + q < le) {
                const uint2 eA = ebuf[i + q];
                const uint2 wA =
                    *(const uint2*)(Ph + (size_t)eA.x * HIDDEN + 4 * ql);
                const float vA = __uint_as_float(eA.y);
                a0 = fmaf(vA, bflo(wA.x), a0);
                a1 = fmaf(vA, bfhi(wA.x), a1);
                a2 = fmaf(vA, bflo(wA.y), a2);
                a3 = fmaf(vA, bfhi(wA.y), a3);
                dA += vA;
            }

            float x0 = a0 + c0, x1 = a1 + c1, x2 = a2 + c2, x3 = a3 + c3;
            float deg = dA + dB;
            x0 += __shfl_xor(x0, 16); x0 += __shfl_xor(x0, 32);
            x1 += __shfl_xor(x1, 16); x1 += __shfl_xor(x1, 32);
            x2 += __shfl_xor(x2, 16); x2 += __shfl_xor(x2, 32);
            x3 += __shfl_xor(x3, 16); x3 += __shfl_xor(x3, 32);
            deg += __shfl_xor(deg, 16); deg += __shfl_xor(deg, 32);
            if (q == 0) {
                float4* dst = (float4*)(user_emb + (size_t)gu * HIDDEN + 4 * ql);
                if (first) {
                    *dst = make_float4(x0, x1, x2, x3);
                } else {
                    const float4 o = *dst;
                    *dst = make_float4(o.x + x0, o.y + x1, o.z + x2, o.w + x3);
                }
                if (ql == 0) {
                    if (first) user_deg[gu] = deg;
                    else user_deg[gu] += deg;
                }
            }
        }
        __syncthreads();    // ebuf/cnt reused next chunk
        first = false;
        cbase += CAP;
    } while (cbase < s1);
}

// ---------------------------------------------------------------------------
// 16 bf16 x 16 fp32 dot for one lane: q points at 32B (2 x uint4).
// ---------------------------------------------------------------------------
__device__ inline float dot16(const uint4* __restrict__ q,
                              const float* __restrict__ ue) {
    float d = 0.0f;
    #pragma unroll
    for (int h = 0; h < 2; ++h) {
        const uint4 v = q[h];
        const unsigned w0 = v.x, w1 = v.y, w2 = v.z, w3 = v.w;
        d = fmaf(ue[h * 8 + 0], bflo(w0), d);
        d = fmaf(ue[h * 8 + 1], bfhi(w0), d);
        d = fmaf(ue[h * 8 + 2], bflo(w1), d);
        d = fmaf(ue[h * 8 + 3], bfhi(w1), d);
        d = fmaf(ue[h * 8 + 4], bflo(w2), d);
        d = fmaf(ue[h * 8 + 5], bfhi(w2), d);
        d = fmaf(ue[h * 8 + 6], bflo(w3), d);
        d = fmaf(ue[h * 8 + 7], bfhi(w3), d);
    }
    return d;
}

// ---------------------------------------------------------------------------
// Pair loss, 4-lane group per pair (lane = 16 components), partial store.
// ---------------------------------------------------------------------------
template <int S>
__global__ void loss4_kernel(const float* __restrict__ user_emb,
                             const float* __restrict__ user_deg,
                             const unsigned short* __restrict__ Qh,
                             const float* __restrict__ b_u,
                             const float* __restrict__ b_i,
                             const int* __restrict__ rows,
                             const int* __restrict__ cols,
                             const int* __restrict__ pos_idx,
                             const int* __restrict__ neg_item_idx,
                             int num_pos,
                             float* __restrict__ partials, int slot_base) {
    const int tid = blockIdx.x * blockDim.x + threadIdx.x;
    const int g = tid >> 2;            // pair index
    const int l = tid & 3;             // lane-in-group: components [16l,16l+16)
    float acc = 0.0f;

    if (g < num_pos) {
        const int e = pos_idx[g];
        const int u = rows[e];
        const int ii = cols[e];
        const float invdeg = 1.0f / user_deg[u];

        float ue[16];
        {
            const float4* uep =
                (const float4*)(user_emb + (size_t)u * HIDDEN + l * 16);
            #pragma unroll
            for (int k = 0; k < 4; ++k) {
                const float4 t4 = uep[k];
                ue[4 * k + 0] = t4.x * invdeg;
                ue[4 * k + 1] = t4.y * invdeg;
                ue[4 * k + 2] = t4.z * invdeg;
                ue[4 * k + 3] = t4.w * invdeg;
            }
        }

        int jarr[S];
        float part[1 + S];
        part[0] = dot16((const uint4*)(Qh + (size_t)ii * HIDDEN + l * 16), ue);
        #pragma unroll
        for (int s = 0; s < S; ++s) {
            const int j = neg_item_idx[(size_t)g * S + s];
            jarr[s] = j;
            part[1 + s] =
                dot16((const uint4*)(Qh + (size_t)j * HIDDEN + l * 16), ue);
        }

        #pragma unroll
        for (int k = 0; k < 1 + S; ++k) {
            part[k] += __shfl_xor(part[k], 1);
            part[k] += __shfl_xor(part[k], 2);
        }

        if (l == 0) {
            const float bu = b_u[u];
            const float r = bu + b_i[ii] + part[0];
            #pragma unroll
            for (int s = 0; s < S; ++s) {
                const float nr = bu + b_i[jarr[s]] + part[1 + s];
                const float diff = 1.0f - (r - nr);
                acc += 0.5f * diff * diff;
            }
        }
    }

    for (int off = 32; off; off >>= 1) acc += __shfl_down(acc, off);
    __shared__ float s_part[16];
    const int wave = threadIdx.x >> 6;
    const int lane = threadIdx.x & 63;
    if (lane == 0) s_part[wave] = acc;
    __syncthreads();
    if (threadIdx.x == 0) {
        float t = 0.0f;
        const int nw = blockDim.x >> 6;
        for (int w = 0; w < nw; ++w) t += s_part[w];
        partials[slot_base + blockIdx.x] = t;
    }
}

// generic fallback (thread per pair), only used if S != 5
__global__ void loss_generic_kernel(const float* __restrict__ user_emb,
                                    const float* __restrict__ user_deg,
                                    const unsigned short* __restrict__ Qh,
                                    const float* __restrict__ b_u,
                                    const float* __restrict__ b_i,
                                    const int* __restrict__ rows,
                                    const int* __restrict__ cols,
                                    const int* __restrict__ pos_idx,
                                    const int* __restrict__ neg_item_idx,
                                    int num_pos, int S,
                                    float* __restrict__ partials,
                                    int slot_base) {
    const int p = blockIdx.x * blockDim.x + threadIdx.x;
    float acc = 0.0f;
    if (p < num_pos) {
        const int e = pos_idx[p];
        const int u = rows[e];
        const int ii = cols[e];
        const float invdeg = 1.0f / user_deg[u];
        float ue[HIDDEN];
        #pragma unroll
        for (int kk = 0; kk < HIDDEN; ++kk)
            ue[kk] = user_emb[(size_t)u * HIDDEN + kk] * invdeg;
        const float bu = b_u[u];
        float dot = 0.0f;
        #pragma unroll
        for (int kk = 0; kk < HIDDEN; ++kk)
            dot = fmaf(ue[kk], bf2f(Qh[(size_t)ii * HIDDEN + kk]), dot);
        const float rr = bu + b_i[ii] + dot;
        for (int s = 0; s < S; ++s) {
            const int j = neg_item_idx[(size_t)p * S + s];
            float dn = 0.0f;
            #pragma unroll
            for (int kk = 0; kk < HIDDEN; ++kk)
                dn = fmaf(ue[kk], bf2f(Qh[(size_t)j * HIDDEN + kk]), dn);
            const float nr = bu + b_i[j] + dn;
            const float diff = 1.0f - (rr - nr);
            acc += 0.5f * diff * diff;
        }
    }
    for (int off = 32; off; off >>= 1) acc += __shfl_down(acc, off);
    __shared__ float s_part[16];
    const int wave = threadIdx.x >> 6;
    const int lane = threadIdx.x & 63;
    if (lane == 0) s_part[wave] = acc;
    __syncthreads();
    if (threadIdx.x == 0) {
        float t = 0.0f;
        const int nw = blockDim.x >> 6;
        for (int w = 0; w < nw; ++w) t += s_part[w];
        partials[slot_base + blockIdx.x] = t;
    }
}

// ---------------------------------------------------------------------------
// Final reduction: sum partial slots + GAMMA bias regularizer -> out[0].
// ---------------------------------------------------------------------------
__global__ void __launch_bounds__(1024)
final_reduce_kernel(const float* __restrict__ partials, int n,
                    const float* __restrict__ b_u, int nu,
                    const float* __restrict__ b_i, int ni,
                    float* __restrict__ out) {
    __shared__ float s[1024];
    const int t = threadIdx.x;
    float a = 0.0f;
    for (int i = t; i < n; i += 1024) a += partials[i];
    float r = 0.0f;
    for (int i = t; i < nu; i += 1024) {
        const float v = b_u[i];
        r = fmaf(v, v, r);
    }
    for (int i = t; i < ni; i += 1024) {
        const float v = b_i[i];
        r = fmaf(v, v, r);
    }
    s[t] = a + 0.5f * GAMMA * r;
    __syncthreads();
    for (int off = 512; off; off >>= 1) {
        if (t < off) s[t] += s[t + off];
        __syncthreads();
    }
    if (t == 0) out[0] = s[0];
}

// ---------------------------------------------------------------------------
extern "C" void kernel_launch(void* const* d_in, const int* in_sizes, int n_in,
                              void* d_out, int out_size, void* d_ws, size_t ws_size,
                              hipStream_t stream) {
    const float* features     = (const float*)d_in[0];
    const float* W_enc        = (const float*)d_in[1];
    const float* b_enc        = (const float*)d_in[2];
    const float* W_p          = (const float*)d_in[3];
    const float* W_q          = (const float*)d_in[4];
    const float* b_u          = (const float*)d_in[5];
    const float* b_i          = (const float*)d_in[6];
    const float* vals         = (const float*)d_in[7];
    const int*   rows         = (const int*)d_in[8];
    const int*   cols         = (const int*)d_in[9];
    const int*   pos_idx      = (const int*)d_in[10];
    const int*   neg_item_idx = (const int*)d_in[11];

    const int num_users  = in_sizes[5];                 // 50000
    const int num_movies = in_sizes[6];                 // 20000
    const int in_feats   = in_sizes[0] / num_movies;    // 128
    const int nnz        = in_sizes[7];                 // 2000000
    const int num_pos    = in_sizes[10];                // 200000
    const int S          = in_sizes[11] / num_pos;      // 5

    const int nbB    = (num_users + BUCKET_W - 1) >> BUCKET_SHIFT;  // 391
    const int ntiles = (nnz + TILE_E - 1) / TILE_E;                 // 245
    const int scanNB = nbB * ntiles;                                // 95795
    const int n1b    = (scanNB + 255) / 256;                        // 375 <= 512

    const int enc_blocks  = (num_movies + 15) / 16;                 // 1250
    const int loss_blocks = (S == 5) ? (int)(((size_t)num_pos * 4 + 255) / 256)
                                     : (num_pos + 255) / 256;
    const int slot_pq   = 0;
    const int slot_loss = enc_blocks;
    const int n_slots   = enc_blocks + loss_blocks;

    // workspace layout (256B-aligned)
    auto align256 = [](size_t x) { return (x + 255) & ~(size_t)255; };
    char* ws = (char*)d_ws;
    size_t off = 0;
    unsigned short* Ph = (unsigned short*)(ws + off);
    off += align256((size_t)num_movies * HIDDEN * 2);
    unsigned short* Qh = (unsigned short*)(ws + off);
    off += align256((size_t)num_movies * HIDDEN * 2);
    uint2* temp     = (uint2*)(ws + off); off += align256((size_t)nnz * 8);
    float* user_emb = (float*)(ws + off); off += align256((size_t)num_users * HIDDEN * 4);
    float* user_deg = (float*)(ws + off); off += align256((size_t)num_users * 4);
    unsigned* tileHistB = (unsigned*)(ws + off); off += align256((size_t)scanNB * 4);
    unsigned* offsB     = (unsigned*)(ws + off); off += align256((size_t)(scanNB + 1) * 4);
    unsigned* sums_b    = (unsigned*)(ws + off); off += align256(512 * 4);
    unsigned* top_b     = (unsigned*)(ws + off); off += align256(512 * 4);
    float* partials     = (float*)(ws + off);    off += align256((size_t)n_slots * 4);

    float* out = (float*)d_out;

    // fused register-blocked encode -> Ph/Qh (bf16) + regularizer partials
    encode_kernel<<<enc_blocks, 256, 0, stream>>>(
        features, W_enc, b_enc, W_p, W_q, Ph, Qh, partials, slot_pq,
        num_movies, in_feats);

    // nnz bucket histogram + scan -> offsB
    tilehist_kernel<<<ntiles, 256, (size_t)nbB * 4, stream>>>(
        rows, nnz, nbB, ntiles, tileHistB);
    chunksum_kernel<<<n1b, 256, 0, stream>>>(tileHistB, scanNB, sums_b);
    scantop_kernel<<<1, 512, 0, stream>>>(sums_b, n1b, top_b, offsB, scanNB, nnz);
    exscan_kernel<<<n1b, 256, 0, stream>>>(tileHistB, scanNB, top_b, offsB);

    // partition -> bucket-major temp
    partition_kernel<<<ntiles, 256, (size_t)nbB * 8, stream>>>(
        rows, cols, vals, nnz, nbB, ntiles, offsB, temp);

    // fused register-staged LDS scatter + gather
    scatter_gather_kernel<<<nbB, 512, 0, stream>>>(
        temp, offsB, Ph, user_emb, user_deg, ntiles, num_users);

    // pair loss -> per-block partials
    if (S == 5) {
        loss4_kernel<5><<<loss_blocks, 256, 0, stream>>>(
            user_emb, user_deg, Qh, b_u, b_i, rows, cols, pos_idx,
            neg_item_idx, num_pos, partials, slot_loss);
    } else {
        loss_generic_kernel<<<loss_blocks, 256, 0, stream>>>(
            user_emb, user_deg, Qh, b_u, b_i, rows, cols, pos_idx,
            neg_item_idx, num_pos, S, partials, slot_loss);
    }

    // final: partial slots + GAMMA bias regularizer
    final_reduce_kernel<<<1, 1024, 0, stream>>>(partials, n_slots,
                                                b_u, num_users,
                                                b_i, num_movies, out);
}